// Round 2
// baseline (118.985 us; speedup 1.0000x reference)
//
#include <hip/hip_runtime.h>

#define H_IN   181
#define W_IN   360
#define NLAT   361
#define NLON   720
#define CIN    16
#define COUT   16
#define KSZ    3
#define NNZ    8192
#define XPLANE (H_IN * W_IN)       // 65160 floats per input channel
#define MAXK   32                  // capacity per (ho,parity,k) segment (mean ~3.8)
#define NPAIR  (NLAT * 2)          // 722 (ho, lon-half) work pairs
#define GRID   1456                // 8 * 182: swizzled (pair, parity) space + 12 dummies

// Fully fused, zero-workspace DISCO transpose conv, round 2.
// Work unit = (ho, lon-half, parity): 1444 blocks x 192 threads (180 active),
// thread owns one output lon. Buckets are built k-SORTED into 3 segments so
// the gather loop has a compile-time accumulator bank; the entry loop is
// unrolled x2 over zero-padded segments for 32-deep load MLP; x is addressed
// with 32-bit indices so loads compile to s[base]+voffset (1 v_add each).
//
// XCD pair-swizzle: blockIdx = r + 8*(2*q + pe) with p = 8q + r, so the two
// parity blocks of a (ho,half) pair share bid%8 (same XCD) and are dispatched
// 8 slots apart -> their interleaved stride-2 output lines can merge in L2.

static __device__ __forceinline__ int rfl_i(int i) {
    return __builtin_amdgcn_readfirstlane(i);
}
static __device__ __forceinline__ float rfl_f(float f) {
    return __uint_as_float(__builtin_amdgcn_readfirstlane(__float_as_uint(f)));
}

__global__ __launch_bounds__(192) void fused_disco_kernel(
    const float* __restrict__ x,        // [CIN][H_IN][W_IN]
    const float* __restrict__ w,        // [COUT][CIN][KSZ]
    const float* __restrict__ bias,     // [COUT]
    const int*   __restrict__ ker_idx,  // [NNZ]
    const int*   __restrict__ row_idx,  // [NNZ]
    const int*   __restrict__ col_idx,  // [NNZ]
    const float* __restrict__ vals,     // [NNZ]
    float* __restrict__ out)            // [COUT][NLAT][NLON]
{
    const int bid   = blockIdx.x;
    const int r     = bid & 7;
    const int inner = bid >> 3;         // [0,182)
    const int pe    = inner & 1;        // longitude parity
    const int p     = (inner >> 1) * 8 + r;
    if (p >= NPAIR) return;             // 12 dummy blocks
    const int ho   = p >> 1;
    const int half = p & 1;
    const int tid  = threadIdx.x;

    __shared__ int   s_ck[3];
    __shared__ int   s_ps[3 * MAXK];    // p >> 1
    __shared__ int   s_xr[3 * MAXK];    // row_idx * W_IN
    __shared__ float s_v [3 * MAXK];

    if (tid < 3) s_ck[tid] = 0;
    __syncthreads();

    // ---- k-sorted bucket scan: entries with out-lat ho, lon parity pe ----
    for (int n = tid; n < NNZ; n += 192) {
        const int c  = col_idx[n];
        const int hi = c / NLON;
        if (hi != ho) continue;
        const int pf = c - hi * NLON;
        if ((pf & 1) != pe) continue;
        const int k    = ker_idx[n];
        const int slot = atomicAdd(&s_ck[k], 1);
        if (slot < MAXK) {
            s_ps[k * MAXK + slot] = pf >> 1;
            s_xr[k * MAXK + slot] = row_idx[n] * W_IN;
            s_v [k * MAXK + slot] = vals[n];
        }
    }
    __syncthreads();

    // ---- clamp + zero-pad each segment to even length (for x2 unroll) ----
    if (tid < 3) {
        int c = s_ck[tid] < MAXK ? s_ck[tid] : MAXK;
        if (c & 1) {
            s_ps[tid * MAXK + c] = 0;
            s_xr[tid * MAXK + c] = 0;
            s_v [tid * MAXK + c] = 0.f;
            ++c;
        }
        s_ck[tid] = c;
    }
    __syncthreads();

    const int ck0 = rfl_i(s_ck[0]);
    const int ck1 = rfl_i(s_ck[1]);
    const int ck2 = rfl_i(s_ck[2]);

    if (tid >= 180) return;
    const int lonIdx = half * 180 + tid;     // == lon >> 1, in [0,360)
    const int lon    = 2 * lonIdx + pe;

    float g0[CIN], g1[CIN], g2[CIN];
#pragma unroll
    for (int c = 0; c < CIN; ++c) { g0[c] = 0.f; g1[c] = 0.f; g2[c] = 0.f; }

    // per-k gather segments: compile-time accumulator bank, x2 entry unroll
#define SEG(K, CK, GK)                                                          \
    for (int e = 0; e < (CK); e += 2) {                                         \
        const int   ps0 = rfl_i(s_ps[(K) * MAXK + e]);                          \
        const int   xr0 = rfl_i(s_xr[(K) * MAXK + e]);                          \
        const float v0  = rfl_f(s_v [(K) * MAXK + e]);                          \
        const int   ps1 = rfl_i(s_ps[(K) * MAXK + e + 1]);                      \
        const int   xr1 = rfl_i(s_xr[(K) * MAXK + e + 1]);                      \
        const float v1  = rfl_f(s_v [(K) * MAXK + e + 1]);                      \
        int y0 = lonIdx - ps0; y0 += (y0 >> 31) & 360;                          \
        int y1 = lonIdx - ps1; y1 += (y1 >> 31) & 360;                          \
        const unsigned i0 = (unsigned)(xr0 + y0);                               \
        const unsigned i1 = (unsigned)(xr1 + y1);                               \
        float a0[CIN], a1[CIN];                                                 \
        _Pragma("unroll")                                                       \
        for (int c = 0; c < CIN; ++c) a0[c] = x[i0 + (unsigned)(c * XPLANE)];   \
        _Pragma("unroll")                                                       \
        for (int c = 0; c < CIN; ++c) a1[c] = x[i1 + (unsigned)(c * XPLANE)];   \
        _Pragma("unroll")                                                       \
        for (int c = 0; c < CIN; ++c) GK[c] += v0 * a0[c];                      \
        _Pragma("unroll")                                                       \
        for (int c = 0; c < CIN; ++c) GK[c] += v1 * a1[c];                      \
    }

    SEG(0, ck0, g0)
    SEG(1, ck1, g1)
    SEG(2, ck2, g2)
#undef SEG

    // ---- epilogue: 16x(16x3) weight mix (w/bias uniform -> s_loads) ----
#pragma unroll
    for (int co = 0; co < COUT; ++co) {
        float s = bias[co];
#pragma unroll
        for (int c = 0; c < CIN; ++c) {
            const int wb = (co * CIN + c) * KSZ;
            s += g0[c] * w[wb + 0];
            s += g1[c] * w[wb + 1];
            s += g2[c] * w[wb + 2];
        }
        out[((size_t)co * NLAT + ho) * NLON + lon] = s;
    }
}

// ---------------------------------------------------------------------------
extern "C" void kernel_launch(void* const* d_in, const int* in_sizes, int n_in,
                              void* d_out, int out_size, void* d_ws, size_t ws_size,
                              hipStream_t stream) {
    const float* x       = (const float*)d_in[0];
    const float* weight  = (const float*)d_in[1];
    const float* bias    = (const float*)d_in[2];
    const int*   ker_idx = (const int*)d_in[3];
    const int*   row_idx = (const int*)d_in[4];
    const int*   col_idx = (const int*)d_in[5];
    const float* vals    = (const float*)d_in[6];
    float* out = (float*)d_out;

    (void)d_ws; (void)ws_size;   // deliberately workspace-free

    fused_disco_kernel<<<GRID, 192, 0, stream>>>(
        x, weight, bias, ker_idx, row_idx, col_idx, vals, out);
}

// Round 3
// 107.372 us; speedup vs baseline: 1.1082x; 1.1082x over previous
//
#include <hip/hip_runtime.h>

#define H_IN   181
#define W_IN   360
#define NLAT   361
#define NLON   720
#define CIN    16
#define COUT   16
#define KSZ    3
#define NNZ    8192
#define XPLANE (H_IN * W_IN)       // 65160 floats per input channel
#define MAXK   32                  // capacity per (ho,pe,k) segment (mean 3.78)

// Fused zero-workspace DISCO transpose conv, round 3.
//
// Block = (ho, lon-half): 722 blocks x 384 threads. Threads 0..191 (waves
// 0-2) own EVEN lons of the half, threads 192..383 (waves 3-5) own ODD lons
// -> waves are parity-pure (192 = 3*64), and the two parity groups of one
// block write complementary 4B halves of the same contiguous 360-column
// span from the same CU -> stride-2 stores merge in L2.
//
// Scan: int4 loads of col_idx (6 iters/thread, was 43 scalar in r2) with a
// range-compare filter (no divide). Buckets are (pe,k)-sorted into 6 LDS
// segments, zero-padded to even length; each wave consumes its parity's 3
// segments with compile-time accumulator banks and a x2 entry unroll
// (32 independent coalesced x loads in flight). Epilogue: 16x(16x3) mix
// with wave-uniform weights (s_loads).

static __device__ __forceinline__ int rfl_i(int i) {
    return __builtin_amdgcn_readfirstlane(i);
}
static __device__ __forceinline__ float rfl_f(float f) {
    return __uint_as_float(__builtin_amdgcn_readfirstlane(__float_as_uint(f)));
}

__global__ __launch_bounds__(384) void fused_disco_kernel(
    const float* __restrict__ x,        // [CIN][H_IN][W_IN]
    const float* __restrict__ w,        // [COUT][CIN][KSZ]
    const float* __restrict__ bias,     // [COUT]
    const int*   __restrict__ ker_idx,  // [NNZ]
    const int*   __restrict__ row_idx,  // [NNZ]
    const int*   __restrict__ col_idx,  // [NNZ]
    const float* __restrict__ vals,     // [NNZ]
    float* __restrict__ out)            // [COUT][NLAT][NLON]
{
    const int bid  = blockIdx.x;        // [0, 722)
    const int ho   = bid >> 1;
    const int half = bid & 1;
    const int tid  = threadIdx.x;

    __shared__ int   s_ck[6];
    __shared__ int   s_ps[6 * MAXK];    // p >> 1
    __shared__ int   s_xr[6 * MAXK];    // row_idx * W_IN
    __shared__ float s_v [6 * MAXK];

    if (tid < 6) s_ck[tid] = 0;
    __syncthreads();

    // ---- int4 scan: entries with out-lat == ho, sorted into (pe,k) segs ----
    const int cbase = ho * NLON;
    const int4* __restrict__ col4 = (const int4*)col_idx;
    for (int n4 = tid; n4 < NNZ / 4; n4 += 384) {
        const int4 c4 = col4[n4];
#pragma unroll
        for (int j = 0; j < 4; ++j) {
            const int c = (j == 0) ? c4.x : (j == 1) ? c4.y : (j == 2) ? c4.z : c4.w;
            const unsigned d = (unsigned)(c - cbase);   // in [0,720) iff hi==ho
            if (d < (unsigned)NLON) {
                const int n    = 4 * n4 + j;
                const int seg  = (int)(d & 1u) * 3 + ker_idx[n];
                const int slot = atomicAdd(&s_ck[seg], 1);
                if (slot < MAXK) {
                    s_ps[seg * MAXK + slot] = (int)(d >> 1);
                    s_xr[seg * MAXK + slot] = row_idx[n] * W_IN;
                    s_v [seg * MAXK + slot] = vals[n];
                }
            }
        }
    }
    __syncthreads();

    // ---- clamp + zero-pad each segment to even length (for x2 unroll) ----
    if (tid < 6) {
        int c = s_ck[tid] < MAXK ? s_ck[tid] : MAXK;
        if (c & 1) {                    // c <= 31 here, pad write stays in-bounds
            s_ps[tid * MAXK + c] = 0;
            s_xr[tid * MAXK + c] = 0;
            s_v [tid * MAXK + c] = 0.f;
            ++c;
        }
        s_ck[tid] = c;
    }
    __syncthreads();

    const int wp    = (tid >= 192) ? 1 : 0;   // wave-pure parity group
    const int local = tid - wp * 192;
    const int segb  = wp * 3;

    const int ck0 = rfl_i(s_ck[segb + 0]);
    const int ck1 = rfl_i(s_ck[segb + 1]);
    const int ck2 = rfl_i(s_ck[segb + 2]);

    if (local >= 180) return;
    const int lonIdx = half * 180 + local;    // == lon >> 1, in [0,360)
    const int lon    = 2 * lonIdx + wp;

    float g0[CIN], g1[CIN], g2[CIN];
#pragma unroll
    for (int c = 0; c < CIN; ++c) { g0[c] = 0.f; g1[c] = 0.f; g2[c] = 0.f; }

    // per-k gather segments: compile-time accumulator bank, x2 entry unroll
#define SEG(K, CK, GK)                                                          \
    for (int e = 0; e < (CK); e += 2) {                                         \
        const int base = (segb + (K)) * MAXK + e;                               \
        const int   ps0 = rfl_i(s_ps[base]);                                    \
        const int   xr0 = rfl_i(s_xr[base]);                                    \
        const float v0  = rfl_f(s_v [base]);                                    \
        const int   ps1 = rfl_i(s_ps[base + 1]);                                \
        const int   xr1 = rfl_i(s_xr[base + 1]);                                \
        const float v1  = rfl_f(s_v [base + 1]);                                \
        int y0 = lonIdx - ps0; y0 += (y0 >> 31) & 360;                          \
        int y1 = lonIdx - ps1; y1 += (y1 >> 31) & 360;                          \
        const unsigned i0 = (unsigned)(xr0 + y0);                               \
        const unsigned i1 = (unsigned)(xr1 + y1);                               \
        float a0[CIN], a1[CIN];                                                 \
        _Pragma("unroll")                                                       \
        for (int c = 0; c < CIN; ++c) a0[c] = x[i0 + (unsigned)(c * XPLANE)];   \
        _Pragma("unroll")                                                       \
        for (int c = 0; c < CIN; ++c) a1[c] = x[i1 + (unsigned)(c * XPLANE)];   \
        _Pragma("unroll")                                                       \
        for (int c = 0; c < CIN; ++c) GK[c] += v0 * a0[c];                      \
        _Pragma("unroll")                                                       \
        for (int c = 0; c < CIN; ++c) GK[c] += v1 * a1[c];                      \
    }

    SEG(0, ck0, g0)
    SEG(1, ck1, g1)
    SEG(2, ck2, g2)
#undef SEG

    // ---- epilogue: 16x(16x3) weight mix (w/bias uniform -> s_loads) ----
#pragma unroll
    for (int co = 0; co < COUT; ++co) {
        float s = bias[co];
#pragma unroll
        for (int c = 0; c < CIN; ++c) {
            const int wb = (co * CIN + c) * KSZ;
            s += g0[c] * w[wb + 0];
            s += g1[c] * w[wb + 1];
            s += g2[c] * w[wb + 2];
        }
        out[((size_t)co * NLAT + ho) * NLON + lon] = s;
    }
}

// ---------------------------------------------------------------------------
extern "C" void kernel_launch(void* const* d_in, const int* in_sizes, int n_in,
                              void* d_out, int out_size, void* d_ws, size_t ws_size,
                              hipStream_t stream) {
    const float* x       = (const float*)d_in[0];
    const float* weight  = (const float*)d_in[1];
    const float* bias    = (const float*)d_in[2];
    const int*   ker_idx = (const int*)d_in[3];
    const int*   row_idx = (const int*)d_in[4];
    const int*   col_idx = (const int*)d_in[5];
    const float* vals    = (const float*)d_in[6];
    float* out = (float*)d_out;

    (void)d_ws; (void)ws_size;   // deliberately workspace-free

    fused_disco_kernel<<<NLAT * 2, 384, 0, stream>>>(
        x, weight, bias, ker_idx, row_idx, col_idx, vals, out);
}

// Round 4
// 93.620 us; speedup vs baseline: 1.2709x; 1.1469x over previous
//
#include <hip/hip_runtime.h>

#define H_IN   181
#define W_IN   360
#define NLAT   361
#define NLON   720
#define CIN    16
#define COUT   16
#define KSZ    3
#define NNZ    8192
#define MAXB   48                          // per (ho,parity) capacity (mean 11.3)
#define SLICE_E (KSZ * H_IN * W_IN * 4)    // ushorts per channel-quad slice
#define NMIX_BLK ((KSZ * H_IN * W_IN + 255) / 256)   // 764 mix blocks

// Round 4: the ws-poison fill is UNCONDITIONAL (rounds 1-3, zero ws use, all
// show the same ~64us floor) -> workspace is free. Reinstate round-0's
// pre-mixed bf16 quad-packed xw (1 x 8B load per entry per thread instead of
// 16 x 4B, no per-thread epilogue mix), plus everything learned since:
// int4 range-compare scan, parity-sorted x4-padded segments, rfl-hoisted
// wave-uniform entry fields, x4 entry unroll, XCD slice-pinning.

static __device__ __forceinline__ unsigned short f2bf(float f) {
    unsigned int u = __float_as_uint(f);
    u = (u + 0x7fffu + ((u >> 16) & 1u)) >> 16;
    return (unsigned short)u;
}
static __device__ __forceinline__ void bf2_to_f2(unsigned int d, float& lo, float& hi) {
    lo = __uint_as_float(d << 16);
    hi = __uint_as_float(d & 0xffff0000u);
}
static __device__ __forceinline__ int rfl_i(int i) {
    return __builtin_amdgcn_readfirstlane(i);
}
static __device__ __forceinline__ float rfl_f(float f) {
    return __uint_as_float(__builtin_amdgcn_readfirstlane(__float_as_uint(f)));
}
__device__ __forceinline__ void fma4(float4& a, float v, const float4& f) {
    a.x += v * f.x; a.y += v * f.y; a.z += v * f.z; a.w += v * f.w;
}
static __device__ __forceinline__ float4 ld_bf4(const unsigned short* p) {
    const uint2 d = *(const uint2*)p;
    float4 f;
    bf2_to_f2(d.x, f.x, f.y);
    bf2_to_f2(d.y, f.z, f.w);
    return f;
}

// ---------------------------------------------------------------------------
// K1: blocks [0,NMIX_BLK) channel-mix into bf16 quad-split xw; blocks
// [NMIX_BLK, NMIX_BLK+NLAT) build one latitude's parity-sorted segments.
// ---------------------------------------------------------------------------
__global__ __launch_bounds__(256) void mix_bucket_kernel(
    const float* __restrict__ x,      // [CIN][H_IN][W_IN]
    const float* __restrict__ w,      // [COUT][CIN][KSZ]
    const int*   __restrict__ ker_idx,
    const int*   __restrict__ row_idx,
    const int*   __restrict__ col_idx,
    const float* __restrict__ vals,
    unsigned short* __restrict__ xw,  // [4][KSZ][H_IN][W_IN][4] bf16
    int*   __restrict__ gcnt,         // [NLAT][2] (padded counts)
    int*   __restrict__ gbase,        // [NLAT][2][MAXB]
    int*   __restrict__ gps,          // [NLAT][2][MAXB]
    float* __restrict__ gv)           // [NLAT][2][MAXB]
{
    const int tid = threadIdx.x;

    if (blockIdx.x >= NMIX_BLK) {
        // ---- parity-sorted bucket build for latitude ho ----
        const int ho = blockIdx.x - NMIX_BLK;
        __shared__ int   s_cnt[2];
        __shared__ int   s_b [2 * MAXB];
        __shared__ int   s_ps[2 * MAXB];
        __shared__ float s_v [2 * MAXB];

        if (tid < 2) s_cnt[tid] = 0;
        if (tid < 2 * MAXB) { s_b[tid] = 0; s_ps[tid] = 0; s_v[tid] = 0.f; }
        __syncthreads();

        const int cbase = ho * NLON;
        const int4* __restrict__ col4 = (const int4*)col_idx;
        for (int n4 = tid; n4 < NNZ / 4; n4 += 256) {
            const int4 c4 = col4[n4];
#pragma unroll
            for (int j = 0; j < 4; ++j) {
                const int c = (j == 0) ? c4.x : (j == 1) ? c4.y : (j == 2) ? c4.z : c4.w;
                const unsigned d = (unsigned)(c - cbase);   // <720 iff lat==ho
                if (d < (unsigned)NLON) {
                    const int n    = 4 * n4 + j;
                    const int pe   = (int)(d & 1u);
                    const int slot = atomicAdd(&s_cnt[pe], 1);
                    if (slot < MAXB) {
                        s_b [pe * MAXB + slot] = (ker_idx[n] * H_IN + row_idx[n]) * (W_IN * 4);
                        s_ps[pe * MAXB + slot] = (int)(d >> 1);
                        s_v [pe * MAXB + slot] = vals[n];
                    }
                }
            }
        }
        __syncthreads();
        if (tid < 2) {
            int c = s_cnt[tid] < MAXB ? s_cnt[tid] : MAXB;
            gcnt[ho * 2 + tid] = (c + 3) & ~3;   // x4-padded; pad slots are zero
        }
        __syncthreads();
        for (int i = tid; i < 2 * MAXB; i += 256) {
            gbase[ho * 2 * MAXB + i] = s_b[i];
            gps  [ho * 2 * MAXB + i] = s_ps[i];
            gv   [ho * 2 * MAXB + i] = s_v[i];
        }
        return;
    }

    // ---- channel mix ----
    __shared__ float sw[COUT * CIN * KSZ];
    for (int i = tid; i < COUT * CIN * KSZ; i += 256) sw[i] = w[i];
    __syncthreads();

    const int idx = blockIdx.x * 256 + tid;          // over KSZ*H_IN*W_IN
    if (idx >= KSZ * H_IN * W_IN) return;
    const int k  = idx / (H_IN * W_IN);
    const int hy = idx - k * (H_IN * W_IN);

    float acc[COUT];
#pragma unroll
    for (int co = 0; co < COUT; ++co) acc[co] = 0.f;

    for (int c = 0; c < CIN; ++c) {
        const float xv = x[c * (H_IN * W_IN) + hy];
#pragma unroll
        for (int co = 0; co < COUT; ++co)
            acc[co] += xv * sw[(co * CIN + c) * KSZ + k];
    }

#pragma unroll
    for (int q = 0; q < 4; ++q) {
        ushort4 b;
        b.x = f2bf(acc[4*q+0]); b.y = f2bf(acc[4*q+1]);
        b.z = f2bf(acc[4*q+2]); b.w = f2bf(acc[4*q+3]);
        *(ushort4*)(xw + (size_t)q * SLICE_E + (size_t)idx * 4) = b;
    }
}

// ---------------------------------------------------------------------------
// K2: gather. grid = 1448 (8*181): r=bid&7 pins quad q=r>>1 to an XCD pair so
// each XCD streams mostly one 1.56MB xw slice (L2-resident). Block covers
// (ho, q); thread t owns lon pair (2t, 2t+1). Parity-sorted segments make
// y = t - ps uniform for both parities; x4 entry unroll = 4 independent 8B
// loads in flight; entry fields rfl-hoisted to SGPRs.
// ---------------------------------------------------------------------------
__global__ __launch_bounds__(384) void gather_kernel(
    const unsigned short* __restrict__ xw,  // [4][KSZ][H_IN][W_IN][4] bf16
    const float* __restrict__ bias,         // [COUT]
    const int*   __restrict__ gcnt,
    const int*   __restrict__ gbase,
    const int*   __restrict__ gps,
    const float* __restrict__ gv,
    float* __restrict__ out)                // [COUT][NLAT][NLON]
{
    const int bid   = blockIdx.x;
    const int r     = bid & 7;
    const int inner = bid >> 3;             // [0,181)
    const int q     = r >> 1;
    const int ho    = inner * 2 + (r & 1);
    if (ho >= NLAT) return;                 // 4 dummy blocks
    const int tid = threadIdx.x;

    __shared__ int   s_c[2];
    __shared__ int   s_b [2 * MAXB];
    __shared__ int   s_ps[2 * MAXB];
    __shared__ float s_v [2 * MAXB];

    if (tid < 2) s_c[tid] = gcnt[ho * 2 + tid];
    if (tid < 2 * MAXB) {
        s_b [tid] = gbase[ho * 2 * MAXB + tid];
        s_ps[tid] = gps  [ho * 2 * MAXB + tid];
        s_v [tid] = gv   [ho * 2 * MAXB + tid];
    }
    __syncthreads();

    const int cntE = rfl_i(s_c[0]);
    const int cntO = rfl_i(s_c[1]);

    if (tid >= 360) return;
    const int t = tid;                      // lon pair (2t, 2t+1)

    const float4 bq = ((const float4*)bias)[q];
    float4 accE = bq, accO = bq;
    const unsigned short* __restrict__ slice = xw + (size_t)q * SLICE_E;

    // x4-unrolled parity segment: counts are multiples of 4, pads have v=0
#define SEG(PE, CNT, ACC)                                                       \
    for (int e = 0; e < (CNT); e += 4) {                                        \
        const int base = (PE) * MAXB + e;                                       \
        int   b0 = rfl_i(s_b[base+0]), b1 = rfl_i(s_b[base+1]);                 \
        int   b2 = rfl_i(s_b[base+2]), b3 = rfl_i(s_b[base+3]);                 \
        int   p0 = rfl_i(s_ps[base+0]), p1 = rfl_i(s_ps[base+1]);               \
        int   p2 = rfl_i(s_ps[base+2]), p3 = rfl_i(s_ps[base+3]);               \
        float v0 = rfl_f(s_v[base+0]), v1 = rfl_f(s_v[base+1]);                 \
        float v2 = rfl_f(s_v[base+2]), v3 = rfl_f(s_v[base+3]);                 \
        int y0 = t - p0; y0 += (y0 >> 31) & 360;                                \
        int y1 = t - p1; y1 += (y1 >> 31) & 360;                                \
        int y2 = t - p2; y2 += (y2 >> 31) & 360;                                \
        int y3 = t - p3; y3 += (y3 >> 31) & 360;                                \
        const float4 f0 = ld_bf4(slice + b0 + 4 * y0);                          \
        const float4 f1 = ld_bf4(slice + b1 + 4 * y1);                          \
        const float4 f2 = ld_bf4(slice + b2 + 4 * y2);                          \
        const float4 f3 = ld_bf4(slice + b3 + 4 * y3);                          \
        fma4(ACC, v0, f0); fma4(ACC, v1, f1);                                   \
        fma4(ACC, v2, f2); fma4(ACC, v3, f3);                                   \
    }

    SEG(0, cntE, accE)
    SEG(1, cntO, accO)
#undef SEG

    const float2 rr[4] = { make_float2(accE.x, accO.x), make_float2(accE.y, accO.y),
                           make_float2(accE.z, accO.z), make_float2(accE.w, accO.w) };
#pragma unroll
    for (int j = 0; j < 4; ++j) {
        const int co = 4 * q + j;
        *(float2*)(out + ((size_t)co * NLAT + ho) * NLON + 2 * t) = rr[j];
    }
}

// ---------------------------------------------------------------------------
extern "C" void kernel_launch(void* const* d_in, const int* in_sizes, int n_in,
                              void* d_out, int out_size, void* d_ws, size_t ws_size,
                              hipStream_t stream) {
    const float* x       = (const float*)d_in[0];
    const float* weight  = (const float*)d_in[1];
    const float* bias    = (const float*)d_in[2];
    const int*   ker_idx = (const int*)d_in[3];
    const int*   row_idx = (const int*)d_in[4];
    const int*   col_idx = (const int*)d_in[5];
    const float* vals    = (const float*)d_in[6];
    float* out = (float*)d_out;

    // workspace layout (ws-poison is unconditional, so ws use is free)
    unsigned short* xw = (unsigned short*)d_ws;          // 6,255,360 B
    int*   gcnt  = (int*)((char*)d_ws + 6255360);        // [NLAT*2]
    int*   gbase = gcnt + 1024;                          // [NLAT*2*MAXB]
    int*   gps   = gbase + NLAT * 2 * MAXB;
    float* gv    = (float*)(gps + NLAT * 2 * MAXB);

    mix_bucket_kernel<<<NMIX_BLK + NLAT, 256, 0, stream>>>(
        x, weight, ker_idx, row_idx, col_idx, vals, xw, gcnt, gbase, gps, gv);
    gather_kernel<<<1448, 384, 0, stream>>>(xw, bias, gcnt, gbase, gps, gv, out);
}